// Round 5
// baseline (180.461 us; speedup 1.0000x reference)
//
#include <hip/hip_runtime.h>

#define NB    16
#define CIN   16
#define COUT  32
#define DIN   32
#define DOUT  30

typedef __attribute__((ext_vector_type(8)))  short  short8;
typedef __attribute__((ext_vector_type(16))) float  f32x16;

static __device__ __forceinline__ unsigned short f2bf_rne(float f) {
    unsigned int u = __builtin_bit_cast(unsigned int, f);
    u += 0x7fffu + ((u >> 16) & 1u);
    return (unsigned short)(u >> 16);
}
static __device__ __forceinline__ float bf2f(unsigned short s) {
    unsigned int u = ((unsigned int)s) << 16;
    return __builtin_bit_cast(float, u);
}

// ---- dynamic-LDS layout (short offsets) ----
// swh [0,13824)   : W-frag hi, 1728 entries x 8   (27.6 KB)
// swl [13824,27648): W-frag lo                     (27.6 KB)
// sxh [27648,46080): x-tile hi, 36 slots x 512     (36.9 KB)
// sxl [46080,64512): x-tile lo                     (36.9 KB)
// sp  at byte 129024: 96 floats                    (384 B)   total 129408 B
#define SWH 0
#define SWL 13824
#define SXH 27648
#define SXL 46080
#define SP_BYTES 129024
#define LDS_BYTES 129408

// ---------------- single fused kernel ----------------
// Grid (htile 0..7, dtile 0..7, b): 512 threads = 8 waves.
// Wave wy: hrow = wy&3 -> h = 4*htile+hrow; dg = (wy>>2)*2 -> outputs d0+dg, d0+dg+1.
// Per block: build W-fragment table (bf16 hi/lo split) + x-tile (6 planes x 6 rows,
// channel-last bf16 hi/lo) in LDS, then 162 MFMAs/wave (32x32x16), fused epilogue.
__global__ __launch_bounds__(512, 1) void conv_one(
    const float* __restrict__ x,
    const float* __restrict__ wgt,
    const float* __restrict__ cbias,
    const float* __restrict__ scal,
    const float* __restrict__ bpar,
    float* __restrict__ out)
{
    extern __shared__ __align__(16) char smem_raw[];
    short* sm = (short*)smem_raw;
    float* sp = (float*)(smem_raw + SP_BYTES);

    const int htile = blockIdx.x;
    const int dtile = blockIdx.y;
    const int b     = blockIdx.z;
    const int tid  = threadIdx.x;
    const int wy   = tid >> 6;
    const int lane = tid & 63;

    if (tid < 32) {
        sp[tid]      = cbias[tid];
        sp[32 + tid] = scal[tid];
        sp[64 + tid] = bpar[tid];
    }

    // ---- W fragments: entry i = s*64 + l; lane l holds A[co=l&31][ci=(l>>5)*8+j] ----
    for (int i = tid; i < 1728; i += 512) {
        const int s = i >> 6, l = i & 63;
        const int co = l & 31, ci0 = (l >> 5) * 8;
        short8 vh, vl;
#pragma unroll
        for (int j = 0; j < 8; ++j) {
            float f = wgt[co * (CIN * 27) + (ci0 + j) * 27 + s];
            unsigned short hb = f2bf_rne(f);
            vh[j] = (short)hb;
            vl[j] = (short)f2bf_rne(f - bf2f(hb));
        }
        *(short8*)(sm + SWH + i * 8) = vh;
        *(short8*)(sm + SWL + i * 8) = vl;
    }

    // ---- x tile: slot pr = p*6+r (plane p 0..5, row r 0..5); within slot [w][ci16] ----
    const int h0 = htile * 4, d0 = dtile * 4;
    for (int c = tid; c < 2304; c += 512) {
        const int oc = c & 1, t = c >> 1;
        const int w = t & 31, pr = t >> 5;
        const int p = pr / 6, r = pr - p * 6;
        int hin = h0 + r; if (hin > 31) hin = 31;   // halo clamps feed masked outputs only
        int din = d0 + p; if (din > 31) din = 31;
        const float* xp = x + ((((b * 16 + oc * 8) * 32 + din) * 32 + hin) * 32 + w);
        short8 vh, vl;
#pragma unroll
        for (int j = 0; j < 8; ++j) {
            float f = xp[j * 32768];                // ci = oc*8 + j
            unsigned short hb = f2bf_rne(f);
            vh[j] = (short)hb;
            vl[j] = (short)f2bf_rne(f - bf2f(hb));
        }
        *(short8*)(sm + SXH + pr * 512 + w * 16 + oc * 8) = vh;
        *(short8*)(sm + SXL + pr * 512 + w * 16 + oc * 8) = vl;
    }
    __syncthreads();

    const int hrow = wy & 3, dg = (wy >> 2) * 2;
    const int h  = h0 + hrow;
    const int da = d0 + dg;                 // da<30 => da<=28 => da+1<=29 always valid
    if (h >= DOUT || da >= DOUT) return;    // only barrier is above

    const int n   = lane & 31;              // output w (30 valid + 2 pad)
    const int oc2 = lane >> 5;              // ci octet
    int cofs[3];
#pragma unroll
    for (int kw = 0; kw < 3; ++kw) {
        int wc = n + kw; if (wc > 31) wc = 31;
        cofs[kw] = wc * 16 + oc2 * 8;
    }

    f32x16 acc0, acc1;
#pragma unroll
    for (int i = 0; i < 16; ++i) { acc0[i] = 0.0f; acc1[i] = 0.0f; }

#pragma unroll
    for (int kh = 0; kh < 3; ++kh) {
        const int rowi = hrow + kh;
#pragma unroll
        for (int kw = 0; kw < 3; ++kw) {
            short8 bh[4], bl[4];
#pragma unroll
            for (int q = 0; q < 4; ++q) {           // planes dg..dg+3, reused across kd
                const int slot = (dg + q) * 6 + rowi;
                bh[q] = *(const short8*)(sm + SXH + slot * 512 + cofs[kw]);
                bl[q] = *(const short8*)(sm + SXL + slot * 512 + cofs[kw]);
            }
#pragma unroll
            for (int kd = 0; kd < 3; ++kd) {
                const int s = kd * 9 + kh * 3 + kw;
                short8 ah = *(const short8*)(sm + SWH + (s * 64 + lane) * 8);
                short8 al = *(const short8*)(sm + SWL + (s * 64 + lane) * 8);
                acc0 = __builtin_amdgcn_mfma_f32_32x32x16_bf16(ah, bh[kd],     acc0, 0, 0, 0);
                acc1 = __builtin_amdgcn_mfma_f32_32x32x16_bf16(ah, bh[kd + 1], acc1, 0, 0, 0);
                acc0 = __builtin_amdgcn_mfma_f32_32x32x16_bf16(ah, bl[kd],     acc0, 0, 0, 0);
                acc1 = __builtin_amdgcn_mfma_f32_32x32x16_bf16(ah, bl[kd + 1], acc1, 0, 0, 0);
                acc0 = __builtin_amdgcn_mfma_f32_32x32x16_bf16(al, bh[kd],     acc0, 0, 0, 0);
                acc1 = __builtin_amdgcn_mfma_f32_32x32x16_bf16(al, bh[kd + 1], acc1, 0, 0, 0);
            }
        }
    }

    if (n < DOUT) {
        const int ob = b * (COUT * 27000) + h * 30 + n;
#pragma unroll
        for (int r = 0; r < 16; ++r) {
            const int co = (r & 3) + 8 * (r >> 2) + 4 * oc2;
            float y0 = acc0[r] + sp[co];
            float t0 = y0 * sp[32 + co];
            float th0 = 1.0f - 2.0f / (__expf(2.0f * t0) + 1.0f);
            float z0 = th0 * sp[64 + co];
            out[ob + co * 27000 + da * 900] = 1.0f / (1.0f + __expf(-z0));

            float y1 = acc1[r] + sp[co];
            float t1 = y1 * sp[32 + co];
            float th1 = 1.0f - 2.0f / (__expf(2.0f * t1) + 1.0f);
            float z1 = th1 * sp[64 + co];
            out[ob + co * 27000 + (da + 1) * 900] = 1.0f / (1.0f + __expf(-z1));
        }
    }
}

// ================= fallback: round-4 verified 2-kernel path =================
#define XS_OFF 57344

__global__ __launch_bounds__(256) void prep_kernel(const float* __restrict__ x,
                                                   const float* __restrict__ wgt,
                                                   char* __restrict__ ws) {
    const int bx  = blockIdx.x;
    const int tid = threadIdx.x;
    if (bx < 4096) {
        const int wy = tid >> 6, lane = tid & 63;
        const int rid = bx * 4 + wy;
        const int h = rid & 31, d = (rid >> 5) & 31, b = rid >> 10;
        const int w = lane >> 1, oc = lane & 1;
        const float* xp = x + ((((size_t)(b * 16 + oc * 8) * 32 + d) * 32 + h) * 32 + w);
        short8 vh, vl;
#pragma unroll
        for (int j = 0; j < 8; ++j) {
            float f = xp[j * 32768];
            unsigned short hb = f2bf_rne(f);
            vh[j] = (short)hb;
            vl[j] = (short)f2bf_rne(f - bf2f(hb));
        }
        char* row = ws + XS_OFF + (size_t)rid * 2048;
        *(short8*)(row + lane * 16)        = vh;
        *(short8*)(row + 1024 + lane * 16) = vl;
    } else if (tid < 64) {
        const int s = bx - 4096;
        const int l = tid;
        const int co = l & 31, ci0 = (l >> 5) * 8;
        short8 vh, vl;
#pragma unroll
        for (int j = 0; j < 8; ++j) {
            float f = wgt[co * (CIN * 27) + (ci0 + j) * 27 + s];
            unsigned short hb = f2bf_rne(f);
            vh[j] = (short)hb;
            vl[j] = (short)f2bf_rne(f - bf2f(hb));
        }
        ((short8*)ws)[s * 64 + l]        = vh;
        ((short8*)ws)[1728 + s * 64 + l] = vl;
    }
}

__global__ __launch_bounds__(256) void conv_main(
    const char* __restrict__ ws,
    const float* __restrict__ cbias,
    const float* __restrict__ scal,
    const float* __restrict__ bpar,
    float* __restrict__ out)
{
    __shared__ __align__(16) short sx[24576];
    __shared__ float sp[96];
    const int htile = blockIdx.x, d2 = blockIdx.y, b = blockIdx.z;
    const int tid = threadIdx.x, wy = tid >> 6, lane = tid & 63;
    if (tid < 32) { sp[tid] = cbias[tid]; sp[32 + tid] = scal[tid]; sp[64 + tid] = bpar[tid]; }
    const int h0 = htile * 4, d0 = d2 * 2;
    const char* xbase = ws + XS_OFF;
    const int psw = lane * 8;
#pragma unroll
    for (int r = wy * 12; r < wy * 12 + 12; ++r) {
        const int buf = r & 1, pr = r >> 1;
        const int p = pr / 6, row = pr - p * 6;
        int hin = h0 + row; if (hin > 31) hin = 31;
        const int rid = (b * 32 + d0 + p) * 32 + hin;
        const short8 v = *((const short8*)(xbase + (size_t)rid * 2048 + buf * 1024) + lane);
        *(short8*)(sx + (pr * 2 + buf) * 512 + psw) = v;
    }
    __syncthreads();
    const int h = h0 + wy;
    if (h >= DOUT) return;
    const int n = lane & 31, oc = lane >> 5;
    int cofs[3];
#pragma unroll
    for (int kw = 0; kw < 3; ++kw) {
        int wc = n + kw; if (wc > 31) wc = 31;
        cofs[kw] = (2 * wc + oc) * 8;
    }
    f32x16 acc0, acc1;
#pragma unroll
    for (int i = 0; i < 16; ++i) { acc0[i] = 0.0f; acc1[i] = 0.0f; }
    const short8* wa = (const short8*)ws;
#pragma unroll
    for (int kh = 0; kh < 3; ++kh) {
        const int rowi = wy + kh;
#pragma unroll
        for (int kw = 0; kw < 3; ++kw) {
            short8 bh[4], bl[4];
#pragma unroll
            for (int p = 0; p < 4; ++p) {
                const short* slot = sx + ((p * 6 + rowi) * 2) * 512;
                bh[p] = *(const short8*)(slot + cofs[kw]);
                bl[p] = *(const short8*)(slot + 512 + cofs[kw]);
            }
#pragma unroll
            for (int kd = 0; kd < 3; ++kd) {
                const int s = kd * 9 + kh * 3 + kw;
                short8 ah = wa[s * 64 + lane];
                short8 al = wa[1728 + s * 64 + lane];
                acc0 = __builtin_amdgcn_mfma_f32_32x32x16_bf16(ah, bh[kd],     acc0, 0, 0, 0);
                acc1 = __builtin_amdgcn_mfma_f32_32x32x16_bf16(ah, bh[kd + 1], acc1, 0, 0, 0);
                acc0 = __builtin_amdgcn_mfma_f32_32x32x16_bf16(ah, bl[kd],     acc0, 0, 0, 0);
                acc1 = __builtin_amdgcn_mfma_f32_32x32x16_bf16(ah, bl[kd + 1], acc1, 0, 0, 0);
                acc0 = __builtin_amdgcn_mfma_f32_32x32x16_bf16(al, bh[kd],     acc0, 0, 0, 0);
                acc1 = __builtin_amdgcn_mfma_f32_32x32x16_bf16(al, bh[kd + 1], acc1, 0, 0, 0);
            }
        }
    }
    if (n < DOUT) {
        const int ob = b * (COUT * 27000) + h * 30 + n;
#pragma unroll
        for (int r = 0; r < 16; ++r) {
            const int co = (r & 3) + 8 * (r >> 2) + 4 * oc;
            float y0 = acc0[r] + sp[co];
            float t0 = y0 * sp[32 + co];
            float th0 = 1.0f - 2.0f / (__expf(2.0f * t0) + 1.0f);
            float z0 = th0 * sp[64 + co];
            out[ob + co * 27000 + d0 * 900] = 1.0f / (1.0f + __expf(-z0));
            float y1 = acc1[r] + sp[co];
            float t1 = y1 * sp[32 + co];
            float th1 = 1.0f - 2.0f / (__expf(2.0f * t1) + 1.0f);
            float z1 = th1 * sp[64 + co];
            out[ob + co * 27000 + (d0 + 1) * 900] = 1.0f / (1.0f + __expf(-z1));
        }
    }
}

// last-resort direct conv (no ws)
__global__ __launch_bounds__(256) void conv3d_direct_fb(
    const float* __restrict__ x, const float* __restrict__ wgt,
    const float* __restrict__ cbias, const float* __restrict__ scal,
    const float* __restrict__ bpar, float* __restrict__ out)
{
    __shared__ float sw[CIN * 27];
    const int bx = blockIdx.x, co = blockIdx.y, b = blockIdx.z;
    const int tid = threadIdx.y * 32 + threadIdx.x;
    for (int i = tid; i < CIN * 27; i += 256) sw[i] = wgt[co * (CIN * 27) + i];
    __syncthreads();
    const float bias = cbias[co], s = scal[co], bp = bpar[co];
    const int dt = bx & 7, ht = bx >> 3;
    const int d0 = dt * 4, h = ht * 8 + threadIdx.y, w = threadIdx.x;
    if (w >= DOUT || h >= DOUT) return;
    int rowoff[6];
#pragma unroll
    for (int dz = 0; dz < 6; ++dz) { int dd = d0 + dz; if (dd > 31) dd = 31; rowoff[dz] = dd * 1024; }
    float acc[4] = {0.f, 0.f, 0.f, 0.f};
    const int xb = b * (CIN * 32768);
    for (int ci = 0; ci < CIN; ++ci) {
        const int cioff = xb + ci * 32768;
        const float* swc = &sw[ci * 27];
#pragma unroll
        for (int kh = 0; kh < 3; ++kh) {
            const int hbase = cioff + (h + kh) * DIN + w;
#pragma unroll
            for (int kw = 0; kw < 3; ++kw) {
                float xv[6];
#pragma unroll
                for (int dz = 0; dz < 6; ++dz) xv[dz] = x[hbase + kw + rowoff[dz]];
#pragma unroll
                for (int kd = 0; kd < 3; ++kd) {
                    const float wv = swc[(kd * 3 + kh) * 3 + kw];
#pragma unroll
                    for (int dd = 0; dd < 4; ++dd) acc[dd] = fmaf(xv[dd + kd], wv, acc[dd]);
                }
            }
        }
    }
    const int obase = (b * COUT + co) * 27000 + h * 30 + w;
#pragma unroll
    for (int dd = 0; dd < 4; ++dd) {
        const int d = d0 + dd;
        if (d < DOUT) {
            float y = acc[dd] + bias;
            float t = y * s;
            float th = 1.0f - 2.0f / (__expf(2.0f * t) + 1.0f);
            float z = th * bp;
            out[obase + d * 900] = 1.0f / (1.0f + __expf(-z));
        }
    }
}

extern "C" void kernel_launch(void* const* d_in, const int* in_sizes, int n_in,
                              void* d_out, int out_size, void* d_ws, size_t ws_size,
                              hipStream_t stream) {
    const float* x     = (const float*)d_in[0];
    const float* wgt   = (const float*)d_in[1];
    const float* cbias = (const float*)d_in[2];
    const float* scal  = (const float*)d_in[3];
    const float* bpar  = (const float*)d_in[4];
    float* out = (float*)d_out;

    // Primary: single fused kernel with 129 KB dynamic LDS (needs raised limit).
    hipError_t aerr = hipFuncSetAttribute((const void*)conv_one,
                                          hipFuncAttributeMaxDynamicSharedMemorySize,
                                          LDS_BYTES);
    if (aerr == hipSuccess) {
        hipLaunchKernelGGL(conv_one, dim3(8, 8, NB), dim3(512), LDS_BYTES, stream,
                           x, wgt, cbias, scal, bpar, out);
        if (hipGetLastError() == hipSuccess) return;   // launched (or recorded) OK
    }
    // Fallback: round-4 verified 2-kernel path.
    const size_t need_full = (size_t)XS_OFF + (size_t)16384 * 2048;
    if (ws_size >= need_full) {
        char* ws = (char*)d_ws;
        hipLaunchKernelGGL(prep_kernel, dim3(4096 + 27), dim3(256), 0, stream, x, wgt, ws);
        hipLaunchKernelGGL(conv_main, dim3(8, 15, NB), dim3(256), 0, stream,
                           ws, cbias, scal, bpar, out);
    } else {
        hipLaunchKernelGGL(conv3d_direct_fb, dim3(32, COUT, NB), dim3(32, 8), 0, stream,
                           x, wgt, cbias, scal, bpar, out);
    }
}